// Round 1
// baseline (281.381 us; speedup 1.0000x reference)
//
#include <hip/hip_runtime.h>
#include <math.h>

// LookupLanguageModel: n-gram backoff LM over a CSR-flattened trie.
// R8: same fused structure as R7, but the batch dimension is split across
// blocks (BGB 32 -> 8, grid.y 1 -> 4). R7 launched only 500 blocks
// (~2 blocks/CU, 2 waves/SIMD) and was latency-bound on the two dependent
// cold-memory stalls (window staging, then scattered trigram probes).
// 2000 blocks (~7 resident/CU at 21.6 KB LDS) quadruple TLP; the 4 blocks
// sharing a v-panel are co-resident so their shared trigram lines dedup in
// L2/L3 and HBM traffic stays ~flat. Everything else is unchanged.

#define MAXN 8
#define BGW  2    // batches per wave
#define BGB  8    // batches per block (4 waves)
#define WI   37   // LDS row stride for ids window (odd => conflict-free)
#define WO   41   // LDS row stride for offsets window (odd)

struct PerB {
  int   ctx[MAXN];
  float bo[MAXN];
  float b1;
  int   hp;
};

__device__ __forceinline__ bool find_child(const int* __restrict__ offsets,
                                           const int* __restrict__ ids,
                                           int q, int t, int U, int P, int S,
                                           int* pos_out) {
  int start = offsets[q] + q;
  int end   = offsets[q + 1] + q + 1;
  int n = end - start;
  if (n > S) n = S;
  if (n <= 0) return false;
  int j = (t < n - 1) ? t : (n - 1);
  if (j < 0) j = 0;
  int x = ids[min(start + j, P - 1) - U];
  if (x == t) { *pos_out = start + j; return true; }
  if (x < t) return false;
  int lo = 0, hi = j - 1;
  while (lo < hi) {
    int mid = (lo + hi) >> 1;
    int xm = ids[min(start + mid, P - 1) - U];
    if (xm < t) lo = mid + 1; else hi = mid;
  }
  if (lo < j) {
    int xm = ids[min(start + lo, P - 1) - U];
    if (xm == t) { *pos_out = start + lo; return true; }
  }
  return false;
}

__device__ __forceinline__ float score_v(const int* __restrict__ offsets,
                                         const int* __restrict__ ids,
                                         const float* __restrict__ logps,
                                         const PerB* __restrict__ pbb,
                                         int v, float lp0,
                                         int N, int U, int O, int P, int S) {
  float last_lp = lp0;
  float last_bo = pbb->b1;
  int hp = pbb->hp;
  int desc = v;
  bool found = true;
  float cur_lp = lp0;
  for (int n = 1; n <= N - 1; ++n) {
    int t = pbb->ctx[(N - 1) - n];
    if (found) {
      int pos;
      found = find_child(offsets, ids, desc, t, U, P, S, &pos);
      if (found) { desc = pos; cur_lp = logps[desc]; }
    }
    float cur_bo = (n == N - 1) ? 0.0f : pbb->bo[n];
    bool clobber = isfinite(cur_lp) && found;
    float newlp = clobber ? cur_lp : (last_lp + cur_bo + last_bo);
    last_bo = clobber ? cur_bo : 0.0f;
    if (hp >= n) last_lp = newlp;
  }
  return last_lp;
}

__global__ void __launch_bounds__(256)
lm_fused(const int* __restrict__ hist, const int* __restrict__ hidx,
         const int* __restrict__ offsets, const int* __restrict__ ids,
         const float* __restrict__ logps, const float* __restrict__ logbs,
         const int* __restrict__ sos_p, const int* __restrict__ N_p,
         const int* __restrict__ S_p,
         float* __restrict__ out,
         int V, int B, int L, int O, int P) {
  __shared__ PerB s_pb[BGB];
  __shared__ int  ids_w[64 * WI];
  __shared__ int  off_w[64 * WO];
  __shared__ int  s_start1[64], s_n1[64], s_shi[64], s_sho[64];

  const int tid  = threadIdx.x;
  const int lane = tid & 63;
  const int w    = tid >> 6;
  const int vbase = blockIdx.x * 64;
  const int v     = vbase + lane;
  const int b0    = blockIdx.y * BGB;
  const int N = *N_p, S = *S_p, sos = *sos_p;
  const int Nc = (N > 0) ? N : 1;
  const int shift = (0 <= sos && sos < V) ? 0 : 1;
  const int U = V + shift + 1 % Nc;
  const int idsN = P - U;

  const bool fast = (N == 3) && (S == 32);

  // ---- inline prep: threads 0..BGB-1 compute per-batch context chain
  if (tid < BGB && N > 1) {
    int b = b0 + tid;
    if (b < B) {
      int pad = N - 1;
      int hp = hidx[b] + pad;
      PerB o;
      o.hp = hp;
      for (int k = 0; k < N - 1; ++k) {
        int r = hp - (N - 1) + k;
        int tok = (r < pad) ? sos : hist[(r - pad) * B + b];
        if (shift && tok == sos) tok = V;
        o.ctx[k] = tok;
      }
      o.b1 = logbs[o.ctx[N - 2]];
      int desc = o.ctx[N - 2];
      bool found = true;
      for (int n = 1; n <= N - 2; ++n) {
        int t = o.ctx[(N - 1) - min(n + 1, N - 1)];
        if (found) {
          int pos;
          found = find_child(offsets, ids, desc, t, U, P, S, &pos);
          if (found) desc = pos;
        }
        o.bo[n] = found ? logbs[min(desc, O - 1)] : 0.0f;
      }
      s_pb[tid] = o;
    }
  }

  if (!fast) {
    __syncthreads();
    if (v < V) {
      float lp0 = logps[v];
      if (N <= 1) {
        for (int ib = w; ib < BGB; ib += 4) {
          int b = b0 + ib;
          if (b < B) out[(size_t)b * V + v] = lp0;
        }
      } else {
        for (int ib = w; ib < BGB; ib += 4) {
          int b = b0 + ib;
          if (b < B)
            out[(size_t)b * V + v] = score_v(offsets, ids, logps, s_pb + ib, v,
                                             lp0, N, U, O, P, S);
        }
      }
    }
    return;
  }

  // ---- cooperative window staging: 4 threads per row, once per v
  {
    int row  = tid >> 2;
    int part = tid & 3;
    int vv = vbase + row;
    if (vv < V) {
      int ov  = offsets[vv];
      int ov1 = offsets[vv + 1];
      int start1 = ov + vv;
      int n1 = ov1 + 1 - ov;
      if (n1 > 32) n1 = 32;
      int* myids = ids_w + row * WI;
      int* myoff = off_w + row * WO;
      int aidx0 = start1 - U;
      int sh_i = 0, sh_o = 0;
      bool vec_ok = (start1 >= 0) && (aidx0 >= 0) &&
                    (((aidx0 & ~3) + 36) <= idsN) &&
                    (((start1 & ~3) + 40) <= O);
      if (vec_ok) {
        int ab = aidx0 & ~3;
        sh_i = aidx0 - ab;
        const int4* ip = (const int4*)(ids + ab);
        for (int k = part; k < 9; k += 4) {
          int4 t = ip[k];
          myids[4 * k + 0] = t.x; myids[4 * k + 1] = t.y;
          myids[4 * k + 2] = t.z; myids[4 * k + 3] = t.w;
        }
        int ob = start1 & ~3;
        sh_o = start1 - ob;
        const int4* op = (const int4*)(offsets + ob);
        for (int k = part; k < 10; k += 4) {
          int4 t = op[k];
          myoff[4 * k + 0] = t.x; myoff[4 * k + 1] = t.y;
          myoff[4 * k + 2] = t.z; myoff[4 * k + 3] = t.w;
        }
      } else {
        for (int j = part; j < 36; j += 4) {
          int ii = min(start1 + j, P - 1) - U;
          ii = max(0, min(ii, idsN - 1));
          myids[j] = ids[ii];
        }
        for (int j = part; j < 40; j += 4) {
          int oo = max(0, min(start1 + j, O - 1));
          myoff[j] = offsets[oo];
        }
      }
      if (part == 0) {
        s_start1[row] = start1; s_n1[row] = n1;
        s_shi[row] = sh_i;      s_sho[row] = sh_o;
      }
    } else if (part == 0) {
      s_start1[row] = 0; s_n1[row] = 0; s_shi[row] = 0; s_sho[row] = 0;
    }
  }
  __syncthreads();
  if (v >= V) return;

  float lp0 = logps[v];
  const int start1 = s_start1[lane];
  const int n1     = s_n1[lane];
  const int sh_i   = s_shi[lane];
  const int sh_o   = s_sho[lane];
  const int* myids = ids_w + lane * WI;
  const int* myoff = off_w + lane * WO;

  const int nb = min(BGB, B - b0);

  // ---- phase A: LDS-only level-1 resolution + trigram candidate addresses
  int j1v[BGW];
  int cc1[BGW];
  int cc2[BGW];
  unsigned f1m = 0, l2m = 0;
#pragma unroll
  for (int i = 0; i < BGW; ++i) {
    int ib = w * BGW + i;
    if (ib >= nb) { j1v[i] = 0; cc1[i] = v; cc2[i] = v; continue; }
    int t1 = s_pb[ib].ctx[1];
    bool found = false;
    int j1 = 0;
    if (n1 > 0) {
      int jj = (t1 < n1 - 1) ? t1 : (n1 - 1);
      if (jj < 0) jj = 0;
      int x = myids[sh_i + jj];
      if (x == t1) { found = true; j1 = jj; }
      else if (x > t1) {
        int lo = 0, hi = jj - 1;
        while (lo < hi) {
          int mid = (lo + hi) >> 1;
          if (myids[sh_i + mid] < t1) lo = mid + 1; else hi = mid;
        }
        if (lo < jj && myids[sh_i + lo] == t1) { found = true; j1 = lo; }
      }
    }
    int c1 = start1 + j1;
    j1v[i] = j1;
    int a1 = min(c1, P - 1);
    cc1[i] = a1;
    int t0 = s_pb[ib].ctx[0];
    int o1 = myoff[sh_o + j1];
    int o2 = myoff[sh_o + j1 + 1];
    int start2 = o1 + c1;
    int n2 = o2 + 1 - o1;
    if (n2 > 32) n2 = 32;
    bool l2ok = found && (n2 > 0);
    int jj2 = (t0 < n2 - 1) ? t0 : (n2 - 1);
    if (jj2 < 0) jj2 = 0;
    int c2 = min(start2 + jj2, P - 1);
    cc2[i] = l2ok ? c2 : a1;   // aliases an already-fetched line when skipped
    f1m |= (found ? 1u : 0u) << i;
    l2m |= (l2ok ? 1u : 0u) << i;
  }

  // ---- phase B: batched global loads, no branches in between
  float lp1v[BGW];
  int   x2v[BGW];
  float sp2v[BGW];
#pragma unroll
  for (int i = 0; i < BGW; ++i) lp1v[i] = logps[cc1[i]];
#pragma unroll
  for (int i = 0; i < BGW; ++i) {
    int ii = cc2[i] - U;
    ii = max(0, min(ii, idsN - 1));
    x2v[i] = __builtin_nontemporal_load(ids + ii);
  }
#pragma unroll
  for (int i = 0; i < BGW; ++i)
    sp2v[i] = __builtin_nontemporal_load(logps + cc2[i]);

  // ---- phase C: finalize (pure ALU; global search fallback is cold)
#pragma unroll
  for (int i = 0; i < BGW; ++i) {
    int ib = w * BGW + i;
    if (ib >= nb) continue;
    bool found = (f1m >> i) & 1u;
    bool l2ok  = (l2m >> i) & 1u;
    int   hp = s_pb[ib].hp;
    float bo1 = s_pb[ib].bo[1];
    float last_bo = s_pb[ib].b1;
    float last_lp = lp0;

    float lp1 = found ? lp1v[i] : lp0;
    bool clob = found && isfinite(lp1);
    float nl = clob ? lp1 : (last_lp + bo1 + last_bo);
    last_bo = clob ? bo1 : 0.0f;
    if (hp >= 1) last_lp = nl;

    bool f2 = false;
    float lp2 = 0.0f;
    if (l2ok) {
      int t0 = s_pb[ib].ctx[0];
      int x2 = x2v[i];
      if (x2 == t0) { f2 = true; lp2 = sp2v[i]; }
      else if (x2 > t0) {
        // cold: sorted-window binary search in global ids
        int j1 = j1v[i];
        int c1 = start1 + j1;
        int o1 = myoff[sh_o + j1];
        int o2 = myoff[sh_o + j1 + 1];
        int start2 = o1 + c1;
        int n2 = o2 + 1 - o1;
        if (n2 > 32) n2 = 32;
        int jj2 = (t0 < n2 - 1) ? t0 : (n2 - 1);
        if (jj2 < 0) jj2 = 0;
        int lo = 0, hi = jj2 - 1;
        while (lo < hi) {
          int mid = (lo + hi) >> 1;
          int im = max(0, min(min(start2 + mid, P - 1) - U, idsN - 1));
          if (ids[im] < t0) lo = mid + 1; else hi = mid;
        }
        if (lo < jj2) {
          int il = max(0, min(min(start2 + lo, P - 1) - U, idsN - 1));
          if (ids[il] == t0) { f2 = true; lp2 = logps[min(start2 + lo, P - 1)]; }
        }
      }
    }
    bool clob2 = f2 && isfinite(lp2);
    float nl2 = clob2 ? lp2 : (last_lp + last_bo);
    if (hp >= 2) last_lp = nl2;

    __builtin_nontemporal_store(last_lp, out + (size_t)(b0 + ib) * V + v);
  }
}

extern "C" void kernel_launch(void* const* d_in, const int* in_sizes, int n_in,
                              void* d_out, int out_size, void* d_ws, size_t ws_size,
                              hipStream_t stream) {
  const int*   hist    = (const int*)d_in[0];
  const int*   hidx    = (const int*)d_in[1];
  const int*   offsets = (const int*)d_in[2];
  const int*   ids     = (const int*)d_in[3];
  const float* logps   = (const float*)d_in[4];
  const float* logbs   = (const float*)d_in[5];
  const int*   sos_p   = (const int*)d_in[6];
  const int*   N_p     = (const int*)d_in[8];
  const int*   S_p     = (const int*)d_in[10];

  int B = in_sizes[1];
  int L = in_sizes[0] / B;
  int O = in_sizes[2];
  int P = in_sizes[4];
  int V = out_size / B;
  float* out = (float*)d_out;

  dim3 grid((V + 63) / 64, (B + BGB - 1) / BGB);
  lm_fused<<<grid, dim3(256), 0, stream>>>(
      hist, hidx, offsets, ids, logps, logbs, sos_p, N_p, S_p, out,
      V, B, L, O, P);
}

// Round 2
// 270.531 us; speedup vs baseline: 1.0401x; 1.0401x over previous
//
#include <hip/hip_runtime.h>
#include <math.h>

// LookupLanguageModel: n-gram backoff LM over a CSR-flattened trie.
// R9: R7's traffic-optimal mapping (one block owns 64 v x ALL 32 batches,
// grid = (500,1)) restored — R8 proved splitting batches costs ~11 us of
// duplicated cache-line traffic. To attack the ~10 us of non-BW
// serialization (R7 ran only 8 waves/CU), the block is widened to 1024
// threads (16 waves), BGW 8 -> 2, staging 16 threads/row. Same unique-line
// footprint by construction; occupancy 8 -> up to 32 waves/CU so the
// streaming (staging) and scattered (trigram probe) phases of different
// waves/blocks overlap 4x deeper.

#define MAXN 8
#define TPB  1024  // threads per block
#define NW   16    // waves per block
#define BGW  2     // batches per wave
#define BGB  32    // batches per block (all of B)
#define WI   37    // LDS row stride for ids window (odd => conflict-free)
#define WO   41    // LDS row stride for offsets window (odd)

struct PerB {
  int   ctx[MAXN];
  float bo[MAXN];
  float b1;
  int   hp;
};

__device__ __forceinline__ bool find_child(const int* __restrict__ offsets,
                                           const int* __restrict__ ids,
                                           int q, int t, int U, int P, int S,
                                           int* pos_out) {
  int start = offsets[q] + q;
  int end   = offsets[q + 1] + q + 1;
  int n = end - start;
  if (n > S) n = S;
  if (n <= 0) return false;
  int j = (t < n - 1) ? t : (n - 1);
  if (j < 0) j = 0;
  int x = ids[min(start + j, P - 1) - U];
  if (x == t) { *pos_out = start + j; return true; }
  if (x < t) return false;
  int lo = 0, hi = j - 1;
  while (lo < hi) {
    int mid = (lo + hi) >> 1;
    int xm = ids[min(start + mid, P - 1) - U];
    if (xm < t) lo = mid + 1; else hi = mid;
  }
  if (lo < j) {
    int xm = ids[min(start + lo, P - 1) - U];
    if (xm == t) { *pos_out = start + lo; return true; }
  }
  return false;
}

__device__ __forceinline__ float score_v(const int* __restrict__ offsets,
                                         const int* __restrict__ ids,
                                         const float* __restrict__ logps,
                                         const PerB* __restrict__ pbb,
                                         int v, float lp0,
                                         int N, int U, int O, int P, int S) {
  float last_lp = lp0;
  float last_bo = pbb->b1;
  int hp = pbb->hp;
  int desc = v;
  bool found = true;
  float cur_lp = lp0;
  for (int n = 1; n <= N - 1; ++n) {
    int t = pbb->ctx[(N - 1) - n];
    if (found) {
      int pos;
      found = find_child(offsets, ids, desc, t, U, P, S, &pos);
      if (found) { desc = pos; cur_lp = logps[desc]; }
    }
    float cur_bo = (n == N - 1) ? 0.0f : pbb->bo[n];
    bool clobber = isfinite(cur_lp) && found;
    float newlp = clobber ? cur_lp : (last_lp + cur_bo + last_bo);
    last_bo = clobber ? cur_bo : 0.0f;
    if (hp >= n) last_lp = newlp;
  }
  return last_lp;
}

__global__ void __launch_bounds__(TPB, 8)
lm_fused(const int* __restrict__ hist, const int* __restrict__ hidx,
         const int* __restrict__ offsets, const int* __restrict__ ids,
         const float* __restrict__ logps, const float* __restrict__ logbs,
         const int* __restrict__ sos_p, const int* __restrict__ N_p,
         const int* __restrict__ S_p,
         float* __restrict__ out,
         int V, int B, int L, int O, int P) {
  __shared__ PerB s_pb[BGB];
  __shared__ int  ids_w[64 * WI];
  __shared__ int  off_w[64 * WO];
  __shared__ int  s_start1[64], s_n1[64], s_shi[64], s_sho[64];

  const int tid  = threadIdx.x;
  const int lane = tid & 63;
  const int w    = tid >> 6;
  const int vbase = blockIdx.x * 64;
  const int v     = vbase + lane;
  const int b0    = blockIdx.y * BGB;
  const int N = *N_p, S = *S_p, sos = *sos_p;
  const int Nc = (N > 0) ? N : 1;
  const int shift = (0 <= sos && sos < V) ? 0 : 1;
  const int U = V + shift + 1 % Nc;
  const int idsN = P - U;

  const bool fast = (N == 3) && (S == 32);

  // ---- inline prep: threads 0..BGB-1 compute per-batch context chain
  if (tid < BGB && N > 1) {
    int b = b0 + tid;
    if (b < B) {
      int pad = N - 1;
      int hp = hidx[b] + pad;
      PerB o;
      o.hp = hp;
      for (int k = 0; k < N - 1; ++k) {
        int r = hp - (N - 1) + k;
        int tok = (r < pad) ? sos : hist[(r - pad) * B + b];
        if (shift && tok == sos) tok = V;
        o.ctx[k] = tok;
      }
      o.b1 = logbs[o.ctx[N - 2]];
      int desc = o.ctx[N - 2];
      bool found = true;
      for (int n = 1; n <= N - 2; ++n) {
        int t = o.ctx[(N - 1) - min(n + 1, N - 1)];
        if (found) {
          int pos;
          found = find_child(offsets, ids, desc, t, U, P, S, &pos);
          if (found) desc = pos;
        }
        o.bo[n] = found ? logbs[min(desc, O - 1)] : 0.0f;
      }
      s_pb[tid] = o;
    }
  }

  if (!fast) {
    __syncthreads();
    if (v < V) {
      float lp0 = logps[v];
      if (N <= 1) {
        for (int ib = w; ib < BGB; ib += NW) {
          int b = b0 + ib;
          if (b < B) out[(size_t)b * V + v] = lp0;
        }
      } else {
        for (int ib = w; ib < BGB; ib += NW) {
          int b = b0 + ib;
          if (b < B)
            out[(size_t)b * V + v] = score_v(offsets, ids, logps, s_pb + ib, v,
                                             lp0, N, U, O, P, S);
        }
      }
    }
    return;
  }

  // ---- cooperative window staging: 16 threads per row, once per v
  {
    int row  = tid >> 4;
    int part = tid & 15;
    int vv = vbase + row;
    if (vv < V) {
      int ov  = offsets[vv];
      int ov1 = offsets[vv + 1];
      int start1 = ov + vv;
      int n1 = ov1 + 1 - ov;
      if (n1 > 32) n1 = 32;
      int* myids = ids_w + row * WI;
      int* myoff = off_w + row * WO;
      int aidx0 = start1 - U;
      int sh_i = 0, sh_o = 0;
      bool vec_ok = (start1 >= 0) && (aidx0 >= 0) &&
                    (((aidx0 & ~3) + 36) <= idsN) &&
                    (((start1 & ~3) + 40) <= O);
      if (vec_ok) {
        int ab = aidx0 & ~3;
        sh_i = aidx0 - ab;
        const int4* ip = (const int4*)(ids + ab);
        for (int k = part; k < 9; k += 16) {
          int4 t = ip[k];
          myids[4 * k + 0] = t.x; myids[4 * k + 1] = t.y;
          myids[4 * k + 2] = t.z; myids[4 * k + 3] = t.w;
        }
        int ob = start1 & ~3;
        sh_o = start1 - ob;
        const int4* op = (const int4*)(offsets + ob);
        for (int k = part; k < 10; k += 16) {
          int4 t = op[k];
          myoff[4 * k + 0] = t.x; myoff[4 * k + 1] = t.y;
          myoff[4 * k + 2] = t.z; myoff[4 * k + 3] = t.w;
        }
      } else {
        for (int j = part; j < 36; j += 16) {
          int ii = min(start1 + j, P - 1) - U;
          ii = max(0, min(ii, idsN - 1));
          myids[j] = ids[ii];
        }
        for (int j = part; j < 40; j += 16) {
          int oo = max(0, min(start1 + j, O - 1));
          myoff[j] = offsets[oo];
        }
      }
      if (part == 0) {
        s_start1[row] = start1; s_n1[row] = n1;
        s_shi[row] = sh_i;      s_sho[row] = sh_o;
      }
    } else if (part == 0) {
      s_start1[row] = 0; s_n1[row] = 0; s_shi[row] = 0; s_sho[row] = 0;
    }
  }
  __syncthreads();
  if (v >= V) return;

  float lp0 = logps[v];
  const int start1 = s_start1[lane];
  const int n1     = s_n1[lane];
  const int sh_i   = s_shi[lane];
  const int sh_o   = s_sho[lane];
  const int* myids = ids_w + lane * WI;
  const int* myoff = off_w + lane * WO;

  const int nb = min(BGB, B - b0);

  // ---- phase A: LDS-only level-1 resolution + trigram candidate addresses
  int j1v[BGW];
  int cc1[BGW];
  int cc2[BGW];
  unsigned f1m = 0, l2m = 0;
#pragma unroll
  for (int i = 0; i < BGW; ++i) {
    int ib = w * BGW + i;
    if (ib >= nb) { j1v[i] = 0; cc1[i] = v; cc2[i] = v; continue; }
    int t1 = s_pb[ib].ctx[1];
    bool found = false;
    int j1 = 0;
    if (n1 > 0) {
      int jj = (t1 < n1 - 1) ? t1 : (n1 - 1);
      if (jj < 0) jj = 0;
      int x = myids[sh_i + jj];
      if (x == t1) { found = true; j1 = jj; }
      else if (x > t1) {
        int lo = 0, hi = jj - 1;
        while (lo < hi) {
          int mid = (lo + hi) >> 1;
          if (myids[sh_i + mid] < t1) lo = mid + 1; else hi = mid;
        }
        if (lo < jj && myids[sh_i + lo] == t1) { found = true; j1 = lo; }
      }
    }
    int c1 = start1 + j1;
    j1v[i] = j1;
    int a1 = min(c1, P - 1);
    cc1[i] = a1;
    int t0 = s_pb[ib].ctx[0];
    int o1 = myoff[sh_o + j1];
    int o2 = myoff[sh_o + j1 + 1];
    int start2 = o1 + c1;
    int n2 = o2 + 1 - o1;
    if (n2 > 32) n2 = 32;
    bool l2ok = found && (n2 > 0);
    int jj2 = (t0 < n2 - 1) ? t0 : (n2 - 1);
    if (jj2 < 0) jj2 = 0;
    int c2 = min(start2 + jj2, P - 1);
    cc2[i] = l2ok ? c2 : a1;   // aliases an already-fetched line when skipped
    f1m |= (found ? 1u : 0u) << i;
    l2m |= (l2ok ? 1u : 0u) << i;
  }

  // ---- phase B: batched global loads, no branches in between
  float lp1v[BGW];
  int   x2v[BGW];
  float sp2v[BGW];
#pragma unroll
  for (int i = 0; i < BGW; ++i) lp1v[i] = logps[cc1[i]];
#pragma unroll
  for (int i = 0; i < BGW; ++i) {
    int ii = cc2[i] - U;
    ii = max(0, min(ii, idsN - 1));
    x2v[i] = __builtin_nontemporal_load(ids + ii);
  }
#pragma unroll
  for (int i = 0; i < BGW; ++i)
    sp2v[i] = __builtin_nontemporal_load(logps + cc2[i]);

  // ---- phase C: finalize (pure ALU; global search fallback is cold)
#pragma unroll
  for (int i = 0; i < BGW; ++i) {
    int ib = w * BGW + i;
    if (ib >= nb) continue;
    bool found = (f1m >> i) & 1u;
    bool l2ok  = (l2m >> i) & 1u;
    int   hp = s_pb[ib].hp;
    float bo1 = s_pb[ib].bo[1];
    float last_bo = s_pb[ib].b1;
    float last_lp = lp0;

    float lp1 = found ? lp1v[i] : lp0;
    bool clob = found && isfinite(lp1);
    float nl = clob ? lp1 : (last_lp + bo1 + last_bo);
    last_bo = clob ? bo1 : 0.0f;
    if (hp >= 1) last_lp = nl;

    bool f2 = false;
    float lp2 = 0.0f;
    if (l2ok) {
      int t0 = s_pb[ib].ctx[0];
      int x2 = x2v[i];
      if (x2 == t0) { f2 = true; lp2 = sp2v[i]; }
      else if (x2 > t0) {
        // cold: sorted-window binary search in global ids
        int j1 = j1v[i];
        int c1 = start1 + j1;
        int o1 = myoff[sh_o + j1];
        int o2 = myoff[sh_o + j1 + 1];
        int start2 = o1 + c1;
        int n2 = o2 + 1 - o1;
        if (n2 > 32) n2 = 32;
        int jj2 = (t0 < n2 - 1) ? t0 : (n2 - 1);
        if (jj2 < 0) jj2 = 0;
        int lo = 0, hi = jj2 - 1;
        while (lo < hi) {
          int mid = (lo + hi) >> 1;
          int im = max(0, min(min(start2 + mid, P - 1) - U, idsN - 1));
          if (ids[im] < t0) lo = mid + 1; else hi = mid;
        }
        if (lo < jj2) {
          int il = max(0, min(min(start2 + lo, P - 1) - U, idsN - 1));
          if (ids[il] == t0) { f2 = true; lp2 = logps[min(start2 + lo, P - 1)]; }
        }
      }
    }
    bool clob2 = f2 && isfinite(lp2);
    float nl2 = clob2 ? lp2 : (last_lp + last_bo);
    if (hp >= 2) last_lp = nl2;

    __builtin_nontemporal_store(last_lp, out + (size_t)(b0 + ib) * V + v);
  }
}

extern "C" void kernel_launch(void* const* d_in, const int* in_sizes, int n_in,
                              void* d_out, int out_size, void* d_ws, size_t ws_size,
                              hipStream_t stream) {
  const int*   hist    = (const int*)d_in[0];
  const int*   hidx    = (const int*)d_in[1];
  const int*   offsets = (const int*)d_in[2];
  const int*   ids     = (const int*)d_in[3];
  const float* logps   = (const float*)d_in[4];
  const float* logbs   = (const float*)d_in[5];
  const int*   sos_p   = (const int*)d_in[6];
  const int*   N_p     = (const int*)d_in[8];
  const int*   S_p     = (const int*)d_in[10];

  int B = in_sizes[1];
  int L = in_sizes[0] / B;
  int O = in_sizes[2];
  int P = in_sizes[4];
  int V = out_size / B;
  float* out = (float*)d_out;

  dim3 grid((V + 63) / 64, (B + BGB - 1) / BGB);
  lm_fused<<<grid, dim3(TPB), 0, stream>>>(
      hist, hidx, offsets, ids, logps, logbs, sos_p, N_p, S_p, out,
      V, B, L, O, P);
}

// Round 3
// 264.425 us; speedup vs baseline: 1.0641x; 1.0231x over previous
//
#include <hip/hip_runtime.h>
#include <math.h>

// LookupLanguageModel: n-gram backoff LM over a CSR-flattened trie.
// R10: R9 structure (one block = 64 v x all 32 batches, 1024 threads,
// ~32 waves/CU) + predicated trigram logps probe. R8/R9 established the
// kernel is BW-bound on unique cache lines (marginal ~5.3 TB/s) and NOT
// latency-bound (4x TLP was a null). ~half the trigram probes miss
// (x2 != t0), so the unconditional logps[cc2] load in phase B wasted
// ~26 MB of 128B lines per launch. It is now issued only by matched
// lanes (exec-mask predication => no transaction for misses), trading a
// dependent load (hidden by 32 waves/CU) for real HBM traffic.

#define MAXN 8
#define TPB  1024  // threads per block
#define NW   16    // waves per block
#define BGW  2     // batches per wave
#define BGB  32    // batches per block (all of B)
#define WI   37    // LDS row stride for ids window (odd => conflict-free)
#define WO   41    // LDS row stride for offsets window (odd)

struct PerB {
  int   ctx[MAXN];
  float bo[MAXN];
  float b1;
  int   hp;
};

__device__ __forceinline__ bool find_child(const int* __restrict__ offsets,
                                           const int* __restrict__ ids,
                                           int q, int t, int U, int P, int S,
                                           int* pos_out) {
  int start = offsets[q] + q;
  int end   = offsets[q + 1] + q + 1;
  int n = end - start;
  if (n > S) n = S;
  if (n <= 0) return false;
  int j = (t < n - 1) ? t : (n - 1);
  if (j < 0) j = 0;
  int x = ids[min(start + j, P - 1) - U];
  if (x == t) { *pos_out = start + j; return true; }
  if (x < t) return false;
  int lo = 0, hi = j - 1;
  while (lo < hi) {
    int mid = (lo + hi) >> 1;
    int xm = ids[min(start + mid, P - 1) - U];
    if (xm < t) lo = mid + 1; else hi = mid;
  }
  if (lo < j) {
    int xm = ids[min(start + lo, P - 1) - U];
    if (xm == t) { *pos_out = start + lo; return true; }
  }
  return false;
}

__device__ __forceinline__ float score_v(const int* __restrict__ offsets,
                                         const int* __restrict__ ids,
                                         const float* __restrict__ logps,
                                         const PerB* __restrict__ pbb,
                                         int v, float lp0,
                                         int N, int U, int O, int P, int S) {
  float last_lp = lp0;
  float last_bo = pbb->b1;
  int hp = pbb->hp;
  int desc = v;
  bool found = true;
  float cur_lp = lp0;
  for (int n = 1; n <= N - 1; ++n) {
    int t = pbb->ctx[(N - 1) - n];
    if (found) {
      int pos;
      found = find_child(offsets, ids, desc, t, U, P, S, &pos);
      if (found) { desc = pos; cur_lp = logps[desc]; }
    }
    float cur_bo = (n == N - 1) ? 0.0f : pbb->bo[n];
    bool clobber = isfinite(cur_lp) && found;
    float newlp = clobber ? cur_lp : (last_lp + cur_bo + last_bo);
    last_bo = clobber ? cur_bo : 0.0f;
    if (hp >= n) last_lp = newlp;
  }
  return last_lp;
}

__global__ void __launch_bounds__(TPB, 8)
lm_fused(const int* __restrict__ hist, const int* __restrict__ hidx,
         const int* __restrict__ offsets, const int* __restrict__ ids,
         const float* __restrict__ logps, const float* __restrict__ logbs,
         const int* __restrict__ sos_p, const int* __restrict__ N_p,
         const int* __restrict__ S_p,
         float* __restrict__ out,
         int V, int B, int L, int O, int P) {
  __shared__ PerB s_pb[BGB];
  __shared__ int  ids_w[64 * WI];
  __shared__ int  off_w[64 * WO];
  __shared__ int  s_start1[64], s_n1[64], s_shi[64], s_sho[64];

  const int tid  = threadIdx.x;
  const int lane = tid & 63;
  const int w    = tid >> 6;
  const int vbase = blockIdx.x * 64;
  const int v     = vbase + lane;
  const int b0    = blockIdx.y * BGB;
  const int N = *N_p, S = *S_p, sos = *sos_p;
  const int Nc = (N > 0) ? N : 1;
  const int shift = (0 <= sos && sos < V) ? 0 : 1;
  const int U = V + shift + 1 % Nc;
  const int idsN = P - U;

  const bool fast = (N == 3) && (S == 32);

  // ---- inline prep: threads 0..BGB-1 compute per-batch context chain
  if (tid < BGB && N > 1) {
    int b = b0 + tid;
    if (b < B) {
      int pad = N - 1;
      int hp = hidx[b] + pad;
      PerB o;
      o.hp = hp;
      for (int k = 0; k < N - 1; ++k) {
        int r = hp - (N - 1) + k;
        int tok = (r < pad) ? sos : hist[(r - pad) * B + b];
        if (shift && tok == sos) tok = V;
        o.ctx[k] = tok;
      }
      o.b1 = logbs[o.ctx[N - 2]];
      int desc = o.ctx[N - 2];
      bool found = true;
      for (int n = 1; n <= N - 2; ++n) {
        int t = o.ctx[(N - 1) - min(n + 1, N - 1)];
        if (found) {
          int pos;
          found = find_child(offsets, ids, desc, t, U, P, S, &pos);
          if (found) desc = pos;
        }
        o.bo[n] = found ? logbs[min(desc, O - 1)] : 0.0f;
      }
      s_pb[tid] = o;
    }
  }

  if (!fast) {
    __syncthreads();
    if (v < V) {
      float lp0 = logps[v];
      if (N <= 1) {
        for (int ib = w; ib < BGB; ib += NW) {
          int b = b0 + ib;
          if (b < B) out[(size_t)b * V + v] = lp0;
        }
      } else {
        for (int ib = w; ib < BGB; ib += NW) {
          int b = b0 + ib;
          if (b < B)
            out[(size_t)b * V + v] = score_v(offsets, ids, logps, s_pb + ib, v,
                                             lp0, N, U, O, P, S);
        }
      }
    }
    return;
  }

  // ---- cooperative window staging: 16 threads per row, once per v
  {
    int row  = tid >> 4;
    int part = tid & 15;
    int vv = vbase + row;
    if (vv < V) {
      int ov  = offsets[vv];
      int ov1 = offsets[vv + 1];
      int start1 = ov + vv;
      int n1 = ov1 + 1 - ov;
      if (n1 > 32) n1 = 32;
      int* myids = ids_w + row * WI;
      int* myoff = off_w + row * WO;
      int aidx0 = start1 - U;
      int sh_i = 0, sh_o = 0;
      bool vec_ok = (start1 >= 0) && (aidx0 >= 0) &&
                    (((aidx0 & ~3) + 36) <= idsN) &&
                    (((start1 & ~3) + 40) <= O);
      if (vec_ok) {
        int ab = aidx0 & ~3;
        sh_i = aidx0 - ab;
        const int4* ip = (const int4*)(ids + ab);
        for (int k = part; k < 9; k += 16) {
          int4 t = ip[k];
          myids[4 * k + 0] = t.x; myids[4 * k + 1] = t.y;
          myids[4 * k + 2] = t.z; myids[4 * k + 3] = t.w;
        }
        int ob = start1 & ~3;
        sh_o = start1 - ob;
        const int4* op = (const int4*)(offsets + ob);
        for (int k = part; k < 10; k += 16) {
          int4 t = op[k];
          myoff[4 * k + 0] = t.x; myoff[4 * k + 1] = t.y;
          myoff[4 * k + 2] = t.z; myoff[4 * k + 3] = t.w;
        }
      } else {
        for (int j = part; j < 36; j += 16) {
          int ii = min(start1 + j, P - 1) - U;
          ii = max(0, min(ii, idsN - 1));
          myids[j] = ids[ii];
        }
        for (int j = part; j < 40; j += 16) {
          int oo = max(0, min(start1 + j, O - 1));
          myoff[j] = offsets[oo];
        }
      }
      if (part == 0) {
        s_start1[row] = start1; s_n1[row] = n1;
        s_shi[row] = sh_i;      s_sho[row] = sh_o;
      }
    } else if (part == 0) {
      s_start1[row] = 0; s_n1[row] = 0; s_shi[row] = 0; s_sho[row] = 0;
    }
  }
  __syncthreads();
  if (v >= V) return;

  float lp0 = logps[v];
  const int start1 = s_start1[lane];
  const int n1     = s_n1[lane];
  const int sh_i   = s_shi[lane];
  const int sh_o   = s_sho[lane];
  const int* myids = ids_w + lane * WI;
  const int* myoff = off_w + lane * WO;

  const int nb = min(BGB, B - b0);

  // ---- phase A: LDS-only level-1 resolution + trigram candidate addresses
  int j1v[BGW];
  int cc1[BGW];
  int cc2[BGW];
  unsigned f1m = 0, l2m = 0;
#pragma unroll
  for (int i = 0; i < BGW; ++i) {
    int ib = w * BGW + i;
    if (ib >= nb) { j1v[i] = 0; cc1[i] = v; cc2[i] = v; continue; }
    int t1 = s_pb[ib].ctx[1];
    bool found = false;
    int j1 = 0;
    if (n1 > 0) {
      int jj = (t1 < n1 - 1) ? t1 : (n1 - 1);
      if (jj < 0) jj = 0;
      int x = myids[sh_i + jj];
      if (x == t1) { found = true; j1 = jj; }
      else if (x > t1) {
        int lo = 0, hi = jj - 1;
        while (lo < hi) {
          int mid = (lo + hi) >> 1;
          if (myids[sh_i + mid] < t1) lo = mid + 1; else hi = mid;
        }
        if (lo < jj && myids[sh_i + lo] == t1) { found = true; j1 = lo; }
      }
    }
    int c1 = start1 + j1;
    j1v[i] = j1;
    int a1 = min(c1, P - 1);
    cc1[i] = a1;
    int t0 = s_pb[ib].ctx[0];
    int o1 = myoff[sh_o + j1];
    int o2 = myoff[sh_o + j1 + 1];
    int start2 = o1 + c1;
    int n2 = o2 + 1 - o1;
    if (n2 > 32) n2 = 32;
    bool l2ok = found && (n2 > 0);
    int jj2 = (t0 < n2 - 1) ? t0 : (n2 - 1);
    if (jj2 < 0) jj2 = 0;
    int c2 = min(start2 + jj2, P - 1);
    cc2[i] = l2ok ? c2 : a1;   // aliases an already-fetched line when skipped
    f1m |= (found ? 1u : 0u) << i;
    l2m |= (l2ok ? 1u : 0u) << i;
  }

  // ---- phase B: batched global loads (bigram logps + trigram id probe)
  float lp1v[BGW];
  int   x2v[BGW];
#pragma unroll
  for (int i = 0; i < BGW; ++i) lp1v[i] = logps[cc1[i]];
#pragma unroll
  for (int i = 0; i < BGW; ++i) {
    int ii = cc2[i] - U;
    ii = max(0, min(ii, idsN - 1));
    x2v[i] = __builtin_nontemporal_load(ids + ii);
  }

  // ---- phase B2: predicated trigram logps — only matched lanes fetch.
  // Misses (x2 != t0, ~half of probes) issue no transaction, saving the
  // wasted 128B logps line per miss.
  float sp2v[BGW];
#pragma unroll
  for (int i = 0; i < BGW; ++i) {
    int ib = w * BGW + i;
    sp2v[i] = 0.0f;
    if (ib < nb) {
      bool l2ok = (l2m >> i) & 1u;
      if (l2ok && x2v[i] == s_pb[ib].ctx[0])
        sp2v[i] = __builtin_nontemporal_load(logps + cc2[i]);
    }
  }

  // ---- phase C: finalize (pure ALU; global search fallback is cold)
#pragma unroll
  for (int i = 0; i < BGW; ++i) {
    int ib = w * BGW + i;
    if (ib >= nb) continue;
    bool found = (f1m >> i) & 1u;
    bool l2ok  = (l2m >> i) & 1u;
    int   hp = s_pb[ib].hp;
    float bo1 = s_pb[ib].bo[1];
    float last_bo = s_pb[ib].b1;
    float last_lp = lp0;

    float lp1 = found ? lp1v[i] : lp0;
    bool clob = found && isfinite(lp1);
    float nl = clob ? lp1 : (last_lp + bo1 + last_bo);
    last_bo = clob ? bo1 : 0.0f;
    if (hp >= 1) last_lp = nl;

    bool f2 = false;
    float lp2 = 0.0f;
    if (l2ok) {
      int t0 = s_pb[ib].ctx[0];
      int x2 = x2v[i];
      if (x2 == t0) { f2 = true; lp2 = sp2v[i]; }
      else if (x2 > t0) {
        // cold: sorted-window binary search in global ids
        int j1 = j1v[i];
        int c1 = start1 + j1;
        int o1 = myoff[sh_o + j1];
        int o2 = myoff[sh_o + j1 + 1];
        int start2 = o1 + c1;
        int n2 = o2 + 1 - o1;
        if (n2 > 32) n2 = 32;
        int jj2 = (t0 < n2 - 1) ? t0 : (n2 - 1);
        if (jj2 < 0) jj2 = 0;
        int lo = 0, hi = jj2 - 1;
        while (lo < hi) {
          int mid = (lo + hi) >> 1;
          int im = max(0, min(min(start2 + mid, P - 1) - U, idsN - 1));
          if (ids[im] < t0) lo = mid + 1; else hi = mid;
        }
        if (lo < jj2) {
          int il = max(0, min(min(start2 + lo, P - 1) - U, idsN - 1));
          if (ids[il] == t0) { f2 = true; lp2 = logps[min(start2 + lo, P - 1)]; }
        }
      }
    }
    bool clob2 = f2 && isfinite(lp2);
    float nl2 = clob2 ? lp2 : (last_lp + last_bo);
    if (hp >= 2) last_lp = nl2;

    __builtin_nontemporal_store(last_lp, out + (size_t)(b0 + ib) * V + v);
  }
}

extern "C" void kernel_launch(void* const* d_in, const int* in_sizes, int n_in,
                              void* d_out, int out_size, void* d_ws, size_t ws_size,
                              hipStream_t stream) {
  const int*   hist    = (const int*)d_in[0];
  const int*   hidx    = (const int*)d_in[1];
  const int*   offsets = (const int*)d_in[2];
  const int*   ids     = (const int*)d_in[3];
  const float* logps   = (const float*)d_in[4];
  const float* logbs   = (const float*)d_in[5];
  const int*   sos_p   = (const int*)d_in[6];
  const int*   N_p     = (const int*)d_in[8];
  const int*   S_p     = (const int*)d_in[10];

  int B = in_sizes[1];
  int L = in_sizes[0] / B;
  int O = in_sizes[2];
  int P = in_sizes[4];
  int V = out_size / B;
  float* out = (float*)d_out;

  dim3 grid((V + 63) / 64, (B + BGB - 1) / BGB);
  lm_fused<<<grid, dim3(TPB), 0, stream>>>(
      hist, hidx, offsets, ids, logps, logbs, sos_p, N_p, S_p, out,
      V, B, L, O, P);
}

// Round 4
// 259.771 us; speedup vs baseline: 1.0832x; 1.0179x over previous
//
#include <hip/hip_runtime.h>
#include <math.h>

// LookupLanguageModel: n-gram backoff LM over a CSR-flattened trie.
// R11: probe-coalescing transpose. R8/R10 proved BW-bound on unique lines
// (~98 MB, of which ~82 MB scattered trigram probes); R9 proved TLP is not
// binding. The remaining lever is DRAM efficiency of the scatter: probe
// line index ~ base + 32*v + t1, so with 16 threads per v and batches
// sorted by t1 (LDS rank-sort), each wave issues 4 clusters of ascending
// near-adjacent lines within 4-KB windows instead of 64 lines strided
// 4 KB apart. Results are routed through an LDS buffer so output stores
// stay v-contiguous/coalesced. Same unique-line footprint by construction.

#define MAXN 8
#define TPB  1024  // threads per block
#define NW   16    // waves per block
#define BGW  2     // batch-slots per thread (16 threads per v x 2 = 32)
#define BGB  32    // batches per block (all of B)
#define WI   37    // LDS row stride for ids window (odd => conflict-free)
#define WO   41    // LDS row stride for offsets window (odd)

struct PerB {
  int   ctx[MAXN];
  float bo[MAXN];
  float b1;
  int   hp;
};

__device__ __forceinline__ bool find_child(const int* __restrict__ offsets,
                                           const int* __restrict__ ids,
                                           int q, int t, int U, int P, int S,
                                           int* pos_out) {
  int start = offsets[q] + q;
  int end   = offsets[q + 1] + q + 1;
  int n = end - start;
  if (n > S) n = S;
  if (n <= 0) return false;
  int j = (t < n - 1) ? t : (n - 1);
  if (j < 0) j = 0;
  int x = ids[min(start + j, P - 1) - U];
  if (x == t) { *pos_out = start + j; return true; }
  if (x < t) return false;
  int lo = 0, hi = j - 1;
  while (lo < hi) {
    int mid = (lo + hi) >> 1;
    int xm = ids[min(start + mid, P - 1) - U];
    if (xm < t) lo = mid + 1; else hi = mid;
  }
  if (lo < j) {
    int xm = ids[min(start + lo, P - 1) - U];
    if (xm == t) { *pos_out = start + lo; return true; }
  }
  return false;
}

__device__ __forceinline__ float score_v(const int* __restrict__ offsets,
                                         const int* __restrict__ ids,
                                         const float* __restrict__ logps,
                                         const PerB* __restrict__ pbb,
                                         int v, float lp0,
                                         int N, int U, int O, int P, int S) {
  float last_lp = lp0;
  float last_bo = pbb->b1;
  int hp = pbb->hp;
  int desc = v;
  bool found = true;
  float cur_lp = lp0;
  for (int n = 1; n <= N - 1; ++n) {
    int t = pbb->ctx[(N - 1) - n];
    if (found) {
      int pos;
      found = find_child(offsets, ids, desc, t, U, P, S, &pos);
      if (found) { desc = pos; cur_lp = logps[desc]; }
    }
    float cur_bo = (n == N - 1) ? 0.0f : pbb->bo[n];
    bool clobber = isfinite(cur_lp) && found;
    float newlp = clobber ? cur_lp : (last_lp + cur_bo + last_bo);
    last_bo = clobber ? cur_bo : 0.0f;
    if (hp >= n) last_lp = newlp;
  }
  return last_lp;
}

__global__ void __launch_bounds__(TPB, 8)
lm_fused(const int* __restrict__ hist, const int* __restrict__ hidx,
         const int* __restrict__ offsets, const int* __restrict__ ids,
         const float* __restrict__ logps, const float* __restrict__ logbs,
         const int* __restrict__ sos_p, const int* __restrict__ N_p,
         const int* __restrict__ S_p,
         float* __restrict__ out,
         int V, int B, int L, int O, int P) {
  __shared__ PerB  s_pb[BGB];
  __shared__ int   ids_w[64 * WI];
  __shared__ int   off_w[64 * WO];
  __shared__ int   s_start1[64], s_n1[64], s_shi[64], s_sho[64];
  __shared__ int   s_order[BGB];
  __shared__ float s_res[BGB][65];   // [batch][v-in-block], stride 65 banks

  const int tid  = threadIdx.x;
  const int lane = tid & 63;
  const int w    = tid >> 6;
  const int vbase = blockIdx.x * 64;
  const int b0    = blockIdx.y * BGB;
  const int N = *N_p, S = *S_p, sos = *sos_p;
  const int Nc = (N > 0) ? N : 1;
  const int shift = (0 <= sos && sos < V) ? 0 : 1;
  const int U = V + shift + 1 % Nc;
  const int idsN = P - U;
  const int nb = min(BGB, B - b0);

  const bool fast = (N == 3) && (S == 32);

  // ---- inline prep: threads 0..BGB-1 compute per-batch context chain.
  // All 32 prep lanes are in wave 0 => LDS ops are wave-ordered, so the
  // rank-sort below may read other lanes' s_pb writes without a barrier.
  if (tid < BGB && N > 1) {
    int b = b0 + tid;
    if (b < B) {
      int pad = N - 1;
      int hp = hidx[b] + pad;
      PerB o;
      o.hp = hp;
      for (int k = 0; k < N - 1; ++k) {
        int r = hp - (N - 1) + k;
        int tok = (r < pad) ? sos : hist[(r - pad) * B + b];
        if (shift && tok == sos) tok = V;
        o.ctx[k] = tok;
      }
      o.b1 = logbs[o.ctx[N - 2]];
      int desc = o.ctx[N - 2];
      bool found = true;
      for (int n = 1; n <= N - 2; ++n) {
        int t = o.ctx[(N - 1) - min(n + 1, N - 1)];
        if (found) {
          int pos;
          found = find_child(offsets, ids, desc, t, U, P, S, &pos);
          if (found) desc = pos;
        }
        o.bo[n] = found ? logbs[min(desc, O - 1)] : 0.0f;
      }
      s_pb[tid] = o;
      if (fast) {
        // rank-sort batches by t1 = ctx[1] so probe addresses ascend
        int myt1 = o.ctx[1];
        int r = 0;
        for (int b2 = 0; b2 < nb; ++b2) {
          int t1b = s_pb[b2].ctx[1];
          r += (t1b < myt1) || (t1b == myt1 && b2 < tid);
        }
        s_order[r] = tid;
      }
    }
  }

  if (!fast) {
    __syncthreads();
    int v = vbase + lane;
    if (v < V) {
      float lp0 = logps[v];
      if (N <= 1) {
        for (int ib = w; ib < BGB; ib += NW) {
          int b = b0 + ib;
          if (b < B) out[(size_t)b * V + v] = lp0;
        }
      } else {
        for (int ib = w; ib < BGB; ib += NW) {
          int b = b0 + ib;
          if (b < B)
            out[(size_t)b * V + v] = score_v(offsets, ids, logps, s_pb + ib, v,
                                             lp0, N, U, O, P, S);
        }
      }
    }
    return;
  }

  // ---- cooperative window staging: 16 threads per row, once per v
  {
    int row  = tid >> 4;
    int part = tid & 15;
    int vv = vbase + row;
    if (vv < V) {
      int ov  = offsets[vv];
      int ov1 = offsets[vv + 1];
      int start1 = ov + vv;
      int n1 = ov1 + 1 - ov;
      if (n1 > 32) n1 = 32;
      int* myids = ids_w + row * WI;
      int* myoff = off_w + row * WO;
      int aidx0 = start1 - U;
      int sh_i = 0, sh_o = 0;
      bool vec_ok = (start1 >= 0) && (aidx0 >= 0) &&
                    (((aidx0 & ~3) + 36) <= idsN) &&
                    (((start1 & ~3) + 40) <= O);
      if (vec_ok) {
        int ab = aidx0 & ~3;
        sh_i = aidx0 - ab;
        const int4* ip = (const int4*)(ids + ab);
        for (int k = part; k < 9; k += 16) {
          int4 t = ip[k];
          myids[4 * k + 0] = t.x; myids[4 * k + 1] = t.y;
          myids[4 * k + 2] = t.z; myids[4 * k + 3] = t.w;
        }
        int ob = start1 & ~3;
        sh_o = start1 - ob;
        const int4* op = (const int4*)(offsets + ob);
        for (int k = part; k < 10; k += 16) {
          int4 t = op[k];
          myoff[4 * k + 0] = t.x; myoff[4 * k + 1] = t.y;
          myoff[4 * k + 2] = t.z; myoff[4 * k + 3] = t.w;
        }
      } else {
        for (int j = part; j < 36; j += 16) {
          int ii = min(start1 + j, P - 1) - U;
          ii = max(0, min(ii, idsN - 1));
          myids[j] = ids[ii];
        }
        for (int j = part; j < 40; j += 16) {
          int oo = max(0, min(start1 + j, O - 1));
          myoff[j] = offsets[oo];
        }
      }
      if (part == 0) {
        s_start1[row] = start1; s_n1[row] = n1;
        s_shi[row] = sh_i;      s_sho[row] = sh_o;
      }
    } else if (part == 0) {
      s_start1[row] = 0; s_n1[row] = 0; s_shi[row] = 0; s_sho[row] = 0;
    }
  }
  __syncthreads();

  // ---- transposed compute: 16 threads per v, batch-slots sorted by t1
  const int g  = tid >> 4;       // v index within block
  const int sl = tid & 15;       // sub-lane: handles slots 2*sl, 2*sl+1
  const int v  = vbase + g;
  const bool vok = (v < V);

  float lp0 = vok ? logps[v] : 0.0f;
  const int start1 = s_start1[g];
  const int n1     = s_n1[g];
  const int sh_i   = s_shi[g];
  const int sh_o   = s_sho[g];
  const int* myids = ids_w + g * WI;
  const int* myoff = off_w + g * WO;

  // ---- phase A: LDS-only level-1 resolution + trigram candidate addresses
  int bidx[BGW];
  int j1v[BGW];
  int cc1[BGW];
  int cc2[BGW];
  unsigned f1m = 0, l2m = 0;
#pragma unroll
  for (int i = 0; i < BGW; ++i) {
    int k = sl * BGW + i;
    if (!vok || k >= nb) {
      bidx[i] = -1; j1v[i] = 0;
      cc1[i] = vok ? v : 0; cc2[i] = cc1[i];
      continue;
    }
    int b = s_order[k];
    bidx[i] = b;
    int t1 = s_pb[b].ctx[1];
    bool found = false;
    int j1 = 0;
    if (n1 > 0) {
      int jj = (t1 < n1 - 1) ? t1 : (n1 - 1);
      if (jj < 0) jj = 0;
      int x = myids[sh_i + jj];
      if (x == t1) { found = true; j1 = jj; }
      else if (x > t1) {
        int lo = 0, hi = jj - 1;
        while (lo < hi) {
          int mid = (lo + hi) >> 1;
          if (myids[sh_i + mid] < t1) lo = mid + 1; else hi = mid;
        }
        if (lo < jj && myids[sh_i + lo] == t1) { found = true; j1 = lo; }
      }
    }
    int c1 = start1 + j1;
    j1v[i] = j1;
    int a1 = min(c1, P - 1);
    cc1[i] = a1;
    int t0 = s_pb[b].ctx[0];
    int o1 = myoff[sh_o + j1];
    int o2 = myoff[sh_o + j1 + 1];
    int start2 = o1 + c1;
    int n2 = o2 + 1 - o1;
    if (n2 > 32) n2 = 32;
    bool l2ok = found && (n2 > 0);
    int jj2 = (t0 < n2 - 1) ? t0 : (n2 - 1);
    if (jj2 < 0) jj2 = 0;
    int c2 = min(start2 + jj2, P - 1);
    cc2[i] = l2ok ? c2 : a1;   // aliases an already-fetched line when skipped
    f1m |= (found ? 1u : 0u) << i;
    l2m |= (l2ok ? 1u : 0u) << i;
  }

  // ---- phase B: batched global loads (bigram logps + trigram id probe)
  float lp1v[BGW];
  int   x2v[BGW];
#pragma unroll
  for (int i = 0; i < BGW; ++i) lp1v[i] = logps[cc1[i]];
#pragma unroll
  for (int i = 0; i < BGW; ++i) {
    int ii = cc2[i] - U;
    ii = max(0, min(ii, idsN - 1));
    x2v[i] = __builtin_nontemporal_load(ids + ii);
  }

  // ---- phase B2: predicated trigram logps — only matched lanes fetch
  float sp2v[BGW];
#pragma unroll
  for (int i = 0; i < BGW; ++i) {
    sp2v[i] = 0.0f;
    if (bidx[i] >= 0) {
      bool l2ok = (l2m >> i) & 1u;
      if (l2ok && x2v[i] == s_pb[bidx[i]].ctx[0])
        sp2v[i] = __builtin_nontemporal_load(logps + cc2[i]);
    }
  }

  // ---- phase C: finalize (pure ALU; global search fallback is cold)
#pragma unroll
  for (int i = 0; i < BGW; ++i) {
    int b = bidx[i];
    if (b < 0) continue;
    bool found = (f1m >> i) & 1u;
    bool l2ok  = (l2m >> i) & 1u;
    int   hp = s_pb[b].hp;
    float bo1 = s_pb[b].bo[1];
    float last_bo = s_pb[b].b1;
    float last_lp = lp0;

    float lp1 = found ? lp1v[i] : lp0;
    bool clob = found && isfinite(lp1);
    float nl = clob ? lp1 : (last_lp + bo1 + last_bo);
    last_bo = clob ? bo1 : 0.0f;
    if (hp >= 1) last_lp = nl;

    bool f2 = false;
    float lp2 = 0.0f;
    if (l2ok) {
      int t0 = s_pb[b].ctx[0];
      int x2 = x2v[i];
      if (x2 == t0) { f2 = true; lp2 = sp2v[i]; }
      else if (x2 > t0) {
        // cold: sorted-window binary search in global ids
        int j1 = j1v[i];
        int c1 = start1 + j1;
        int o1 = myoff[sh_o + j1];
        int o2 = myoff[sh_o + j1 + 1];
        int start2 = o1 + c1;
        int n2 = o2 + 1 - o1;
        if (n2 > 32) n2 = 32;
        int jj2 = (t0 < n2 - 1) ? t0 : (n2 - 1);
        if (jj2 < 0) jj2 = 0;
        int lo = 0, hi = jj2 - 1;
        while (lo < hi) {
          int mid = (lo + hi) >> 1;
          int im = max(0, min(min(start2 + mid, P - 1) - U, idsN - 1));
          if (ids[im] < t0) lo = mid + 1; else hi = mid;
        }
        if (lo < jj2) {
          int il = max(0, min(min(start2 + lo, P - 1) - U, idsN - 1));
          if (ids[il] == t0) { f2 = true; lp2 = logps[min(start2 + lo, P - 1)]; }
        }
      }
    }
    bool clob2 = f2 && isfinite(lp2);
    float nl2 = clob2 ? lp2 : (last_lp + last_bo);
    if (hp >= 2) last_lp = nl2;

    s_res[b][g] = last_lp;
  }

  // ---- store routing: back to v-contiguous order for coalesced writes
  __syncthreads();
#pragma unroll
  for (int q = 0; q < 2; ++q) {
    int ib = w * 2 + q;
    int vv = vbase + lane;
    if (ib < nb && vv < V)
      __builtin_nontemporal_store(s_res[ib][lane],
                                  out + (size_t)(b0 + ib) * V + vv);
  }
}

extern "C" void kernel_launch(void* const* d_in, const int* in_sizes, int n_in,
                              void* d_out, int out_size, void* d_ws, size_t ws_size,
                              hipStream_t stream) {
  const int*   hist    = (const int*)d_in[0];
  const int*   hidx    = (const int*)d_in[1];
  const int*   offsets = (const int*)d_in[2];
  const int*   ids     = (const int*)d_in[3];
  const float* logps   = (const float*)d_in[4];
  const float* logbs   = (const float*)d_in[5];
  const int*   sos_p   = (const int*)d_in[6];
  const int*   N_p     = (const int*)d_in[8];
  const int*   S_p     = (const int*)d_in[10];

  int B = in_sizes[1];
  int L = in_sizes[0] / B;
  int O = in_sizes[2];
  int P = in_sizes[4];
  int V = out_size / B;
  float* out = (float*)d_out;

  dim3 grid((V + 63) / 64, (B + BGB - 1) / BGB);
  lm_fused<<<grid, dim3(TPB), 0, stream>>>(
      hist, hidx, offsets, ids, logps, logbs, sos_p, N_p, S_p, out,
      V, B, L, O, P);
}